// Round 6
// baseline (3409.706 us; speedup 1.0000x reference)
//
#include <hip/hip_runtime.h>
#include <hip/hip_bf16.h>

#define HID   100
#define SEQ   480
#define INP   640
#define NCLS  307200
#define G4    400
#define TILE  16
#define NTILE 30
#define RING  4

typedef _Float16 h2t   __attribute__((ext_vector_type(2)));
typedef _Float16 f16x8 __attribute__((ext_vector_type(8)));
typedef float    f32x4 __attribute__((ext_vector_type(4)));

__device__ __forceinline__ float fast_sigmoid(float x) {
    return __builtin_amdgcn_rcpf(1.f + __expf(-x));
}
__device__ __forceinline__ float fast_tanh(float x) {
    return 1.f - 2.f * __builtin_amdgcn_rcpf(__expf(2.f * x) + 1.f);
}
__device__ __forceinline__ int ld_acq(const int* p) {
    return __hip_atomic_load(p, __ATOMIC_ACQUIRE, __HIP_MEMORY_SCOPE_AGENT);
}
__device__ __forceinline__ void st_rel(int* p, int v) {
    __hip_atomic_store(p, v, __ATOMIC_RELEASE, __HIP_MEMORY_SCOPE_AGENT);
}
__device__ __forceinline__ f16x8 zero8() {
    f16x8 v;
    #pragma unroll
    for (int i = 0; i < 8; ++i) v[i] = (_Float16)0.f;
    return v;
}
__device__ __forceinline__ f16x8 cvt8(float4 a, float4 b) {
    f16x8 v;
    v[0] = (_Float16)a.x; v[1] = (_Float16)a.y;
    v[2] = (_Float16)a.z; v[3] = (_Float16)a.w;
    v[4] = (_Float16)b.x; v[5] = (_Float16)b.y;
    v[6] = (_Float16)b.z; v[7] = (_Float16)b.w;
    return v;
}
__device__ __forceinline__ f16x8 cvt4z(float4 a) {
    f16x8 v = zero8();
    v[0] = (_Float16)a.x; v[1] = (_Float16)a.y;
    v[2] = (_Float16)a.z; v[3] = (_Float16)a.w;
    return v;
}

// ---------------------------------------------------------------------------
// stage_kernel: 244 blocks.
//   blocks 0..3   : lstm layer l (serial recurrence, Whh only)
//   blocks 4..243 : proj workers, p = bid-4 -> l = p/60, t = (p%60)/2,
//                   nh = p&1 (column half)
// ---------------------------------------------------------------------------
__global__ __launch_bounds__(256, 1) void stage_kernel(
    const float* __restrict__ xin,    // [480][640] stage input
    const float* __restrict__ Wih0,   // [400][640]
    const float* __restrict__ WihR,   // [3][400][100]
    const float* __restrict__ Whh,    // [4][400][100]
    const float* __restrict__ bih,    // [4][400]
    const float* __restrict__ bhh,    // [4][400]
    float* __restrict__ ring,         // [4][RING][16][400]
    _Float16* __restrict__ hseq16,    // [4][480][104] (cols 100..103 zero)
    int* __restrict__ flags)          // [128]
{
    const int bid = blockIdx.x;
    const int tid = threadIdx.x;
    int* hflag  = flags;        // [4]
    int* rdflag = flags + 4;    // [4]
    int* xpflag = flags + 8;    // [120]

    if (bid >= 4) {
        // ================= proj worker (MFMA) =================
        const int p  = bid - 4;
        const int l  = p / 60;
        const int r6 = p % 60;
        const int t  = r6 >> 1;
        const int nh = r6 & 1;
        const int t0 = t * TILE;
        const int lane = tid & 63;
        const int wid  = tid >> 6;
        const int col  = lane & 15;
        const int kb   = lane >> 4;
        const int tile_lo = nh * 13;
        const int tile_hi = nh ? 25 : 13;

        if (l > 0) {
            while (ld_acq(&hflag[l - 1]) < t0 + TILE) __builtin_amdgcn_s_sleep(8);
        }
        if (t >= RING) {
            while (ld_acq(&rdflag[l]) < t - (RING - 1)) __builtin_amdgcn_s_sleep(8);
        }

        float* slot = ring + ((size_t)l * RING + (t & (RING - 1))) * (TILE * G4);

        if (l == 0) {
            f16x8 af[20];
            const float* arow = xin + (size_t)(t0 + col) * INP;
            #pragma unroll
            for (int ks = 0; ks < 20; ++ks) {
                const float* ap = arow + ks * 32 + kb * 8;
                af[ks] = cvt8(*(const float4*)ap, *(const float4*)(ap + 4));
            }
            for (int tile = tile_lo + wid; tile < tile_hi; tile += 4) {
                const int n = tile * 16 + col;
                const float* brow = Wih0 + (size_t)n * INP;
                const float bn = bih[n] + bhh[n];
                f32x4 acc = {bn, bn, bn, bn};
                #pragma unroll
                for (int ks = 0; ks < 20; ++ks) {
                    const float* bp = brow + ks * 32 + kb * 8;
                    f16x8 bf = cvt8(*(const float4*)bp, *(const float4*)(bp + 4));
                    acc = __builtin_amdgcn_mfma_f32_16x16x32_f16(af[ks], bf, acc, 0, 0, 0);
                }
                const int u = n % 100, g = n / 100;
                #pragma unroll
                for (int r = 0; r < 4; ++r)
                    slot[(size_t)(kb * 4 + r) * G4 + u * 4 + g] = acc[r];
            }
        } else {
            f16x8 af[4];
            const _Float16* arow = hseq16 + ((size_t)(l - 1) * SEQ + t0 + col) * 104;
            af[0] = *(const f16x8*)(arow + kb * 8);
            af[1] = *(const f16x8*)(arow + 32 + kb * 8);
            af[2] = *(const f16x8*)(arow + 64 + kb * 8);
            af[3] = (kb == 0) ? *(const f16x8*)(arow + 96) : zero8();
            for (int tile = tile_lo + wid; tile < tile_hi; tile += 4) {
                const int n = tile * 16 + col;
                const float* brow = WihR + ((size_t)(l - 1) * G4 + n) * HID;
                const float bn = bih[l * G4 + n] + bhh[l * G4 + n];
                f32x4 acc = {bn, bn, bn, bn};
                #pragma unroll
                for (int ks = 0; ks < 3; ++ks) {
                    const float* bp = brow + ks * 32 + kb * 8;
                    f16x8 bf = cvt8(*(const float4*)bp, *(const float4*)(bp + 4));
                    acc = __builtin_amdgcn_mfma_f32_16x16x32_f16(af[ks], bf, acc, 0, 0, 0);
                }
                f16x8 bf3 = (kb == 0) ? cvt4z(*(const float4*)(brow + 96)) : zero8();
                acc = __builtin_amdgcn_mfma_f32_16x16x32_f16(af[3], bf3, acc, 0, 0, 0);
                const int u = n % 100, g = n / 100;
                #pragma unroll
                for (int r = 0; r < 4; ++r)
                    slot[(size_t)(kb * 4 + r) * G4 + u * 4 + g] = acc[r];
            }
        }
        __syncthreads();   // drain stores (compiler emits vmcnt(0))
        if (tid == 0)
            __hip_atomic_fetch_add(&xpflag[l * NTILE + t], 1, __ATOMIC_RELEASE,
                                   __HIP_MEMORY_SCOPE_AGENT);
        return;
    }

    // ================= lstm layer block (256 thr, 4 waves) =================
    // kh = tid>>7 (k-half: 52 k-values), j = tid&127. Owner = kh0 & j<100.
    __shared__ __align__(16) float xp_lds[TILE * G4];   // 25.6 KB
    __shared__ __align__(16) uint  hf16[17][64];        // h rows, f16x2 packed
    __shared__ __align__(16) float4 parts[104];         // kh1 partial sums

    const int l    = bid;
    const int kh   = tid >> 7;
    const int j    = tid & 127;
    const int lane = tid & 63;
    const bool own = (kh == 0) && (j < 100);

    // ---- weights: 4 gates x 52 k as f16x2 (104 VGPRs) ----
    h2t wv[4][26];
    const int jj = (j < 100) ? j : 99;
    #pragma unroll
    for (int g = 0; g < 4; ++g) {
        const float* row = Whh + ((size_t)(l * G4 + g * 100 + jj)) * HID + kh * 52;
        #pragma unroll
        for (int q = 0; q < 13; ++q) {
            float4 f = (kh == 0 || q < 12) ? *(const float4*)(row + 4 * q)
                                           : make_float4(0.f, 0.f, 0.f, 0.f);
            wv[g][2 * q]     = h2t{(_Float16)f.x, (_Float16)f.y};
            wv[g][2 * q + 1] = h2t{(_Float16)f.z, (_Float16)f.w};
        }
    }

    for (int i = tid; i < 17 * 64; i += 256) ((uint*)hf16)[i] = 0u;
    float c = 0.f;
    _Float16* hseq_own = hseq16 + (size_t)l * SEQ * 104;
    __syncthreads();

    for (int t = 0; t < NTILE; ++t) {
        const int t0 = t * TILE;

        // ---- wait xp tile (both worker halves), copy ring -> LDS ----
        while (ld_acq(&xpflag[l * NTILE + t]) < 2) __builtin_amdgcn_s_sleep(2);
        {
            const float4* src = (const float4*)(ring +
                ((size_t)l * RING + (t & (RING - 1))) * (TILE * G4));
            float4* dst = (float4*)xp_lds;
            for (int i = tid; i < TILE * G4 / 4; i += 256) dst[i] = src[i];
        }
        __syncthreads();
        if (tid == 0) st_rel(&rdflag[l], t + 1);

        // ---- 16 recurrent steps ----
        for (int tt = 0; tt < TILE; ++tt) {
            // distributed h read: lane c (c<13) holds dwords 2c,2c+1 of half
            uint2 hv = *(const uint2*)(&hf16[tt][kh * 26 + ((lane & 15) << 1)]);

            float e0 = 0.f, e1 = 0.f, e2 = 0.f, e3 = 0.f;
            float o0 = 0.f, o1 = 0.f, o2 = 0.f, o3 = 0.f;
            #pragma unroll
            for (int d = 0; d < 26; d += 2) {
                uint ha_u = (uint)__builtin_amdgcn_readlane((int)hv.x, d >> 1);
                uint hb_u = (uint)__builtin_amdgcn_readlane((int)hv.y, d >> 1);
                h2t ha = __builtin_bit_cast(h2t, ha_u);
                h2t hb = __builtin_bit_cast(h2t, hb_u);
                e0 = __builtin_amdgcn_fdot2(wv[0][d], ha, e0, false);
                e1 = __builtin_amdgcn_fdot2(wv[1][d], ha, e1, false);
                e2 = __builtin_amdgcn_fdot2(wv[2][d], ha, e2, false);
                e3 = __builtin_amdgcn_fdot2(wv[3][d], ha, e3, false);
                o0 = __builtin_amdgcn_fdot2(wv[0][d + 1], hb, o0, false);
                o1 = __builtin_amdgcn_fdot2(wv[1][d + 1], hb, o1, false);
                o2 = __builtin_amdgcn_fdot2(wv[2][d + 1], hb, o2, false);
                o3 = __builtin_amdgcn_fdot2(wv[3][d + 1], hb, o3, false);
            }
            if (kh == 1 && j < 100)
                parts[j] = make_float4(e0 + o0, e1 + o1, e2 + o2, e3 + o3);
            __syncthreads();

            if (own) {
                float4 q  = parts[j];
                float4 xq = *(const float4*)(xp_lds + tt * G4 + (j << 2));
                float gi = e0 + o0 + q.x + xq.x;
                float gf = e1 + o1 + q.y + xq.y;
                float gg = e2 + o2 + q.z + xq.z;
                float go = e3 + o3 + q.w + xq.w;
                float si = fast_sigmoid(gi);
                float sf = fast_sigmoid(gf);
                float so = fast_sigmoid(go);
                float tg = fast_tanh(gg);
                c = sf * c + si * tg;
                float h = so * fast_tanh(c);
                ((_Float16*)&hf16[tt + 1][0])[j] = (_Float16)h;
            }
            __syncthreads();
        }

        // ---- flush rows 1..16 -> hseq16[t0..t0+15]; roll row16 -> row0 ----
        for (int i = tid; i < 16 * 52; i += 256) {
            const int rr = i / 52, dd = i % 52;
            ((uint*)hseq_own)[(size_t)(t0 + rr) * 52 + dd] = hf16[rr + 1][dd];
        }
        if (tid < 52) hf16[0][tid] = hf16[16][tid];
        __syncthreads();   // drains global stores (vmcnt(0)) + LDS
        if (tid == 0) st_rel(&hflag[l], t0 + TILE);
    }
}

// ---------------------------------------------------------------------------
// fc_blend: out[c] = dot(h_last, fcW[c]) + fcb[c]; optional (.+blend)*0.5
// ---------------------------------------------------------------------------
__global__ __launch_bounds__(256) void fc_blend(
    const _Float16* __restrict__ hlast,  // [104] padded row
    const float* __restrict__ fcW,       // [NCLS][HID]
    const float* __restrict__ fcb,       // [NCLS]
    const float* __restrict__ blend,     // [NCLS] or nullptr
    float* __restrict__ outp, int do_blend)
{
    __shared__ __align__(16) float h_lds[HID + 4];
    const int tid = threadIdx.x;
    if (tid < 104) h_lds[tid] = (tid < 100) ? (float)hlast[tid] : 0.f;
    __syncthreads();

    const int cidx = blockIdx.x * 256 + tid;
    const float4* wr = reinterpret_cast<const float4*>(fcW + (size_t)cidx * HID);
    float acc = fcb[cidx];
    #pragma unroll
    for (int k = 0; k < 25; ++k) {
        float4 w4 = wr[k];
        float4 h4 = reinterpret_cast<const float4*>(h_lds)[k];
        acc = fmaf(w4.x, h4.x, acc);
        acc = fmaf(w4.y, h4.y, acc);
        acc = fmaf(w4.z, h4.z, acc);
        acc = fmaf(w4.w, h4.w, acc);
    }
    if (do_blend) acc = (acc + blend[cidx]) * 0.5f;
    outp[cidx] = acc;
}

// ---------------------------------------------------------------------------
extern "C" void kernel_launch(void* const* d_in, const int* in_sizes, int n_in,
                              void* d_out, int out_size, void* d_ws, size_t ws_size,
                              hipStream_t stream)
{
    const float* x    = (const float*)d_in[0];
    const float* xn   = (const float*)d_in[1];
    const float* xnn  = (const float*)d_in[2];
    const float* Wih0 = (const float*)d_in[3];  // (3, 400, 640)
    const float* WihR = (const float*)d_in[4];  // (3, 3, 400, 100)
    const float* Whh  = (const float*)d_in[5];  // (3, 4, 400, 100)
    const float* bih  = (const float*)d_in[6];  // (3, 4, 400)
    const float* bhh  = (const float*)d_in[7];  // (3, 4, 400)
    const float* fcW  = (const float*)d_in[8];  // (3, 307200, 100)
    const float* fcb  = (const float*)d_in[9];  // (3, 307200)
    float* outp = (float*)d_out;
    float* ws = (float*)d_ws;

    float*     ring   = ws;                                  // 102400 f32
    _Float16*  hseq16 = (_Float16*)(ws + 102400);            // 199680 f16
    float*     cur    = ws + 102400 + 99840;                 // 307200 f32
    int*       flags  = (int*)(ws + 102400 + 99840 + 307200);// 3*128 ints

    hipMemsetAsync(flags, 0, 3 * 128 * sizeof(int), stream);

    for (int s = 0; s < 3; ++s) {
        const float* stage_in = (s == 0) ? x : cur;

        stage_kernel<<<4 + 240, 256, 0, stream>>>(
            stage_in,
            Wih0 + (size_t)s * G4 * INP,
            WihR + (size_t)s * 3 * G4 * HID,
            Whh  + (size_t)s * 4 * G4 * HID,
            bih  + (size_t)s * 4 * G4,
            bhh  + (size_t)s * 4 * G4,
            ring, hseq16, flags + s * 128);

        const float* blend = (s == 0) ? xn : (s == 1) ? xnn : nullptr;
        float* dst = (s == 2) ? outp : cur;
        fc_blend<<<NCLS / 256, 256, 0, stream>>>(
            hseq16 + ((size_t)3 * SEQ + SEQ - 1) * 104,
            fcW + (size_t)s * NCLS * HID, fcb + (size_t)s * NCLS,
            blend, dst, (s < 2) ? 1 : 0);
    }
}

// Round 7
// 2301.668 us; speedup vs baseline: 1.4814x; 1.4814x over previous
//
#include <hip/hip_runtime.h>
#include <hip/hip_bf16.h>

#define HID   100
#define SEQ   480
#define INP   640
#define NCLS  307200
#define G4    400
#define TILE  16
#define NTILE 30
#define RING  4

typedef _Float16 h2t   __attribute__((ext_vector_type(2)));
typedef _Float16 f16x8 __attribute__((ext_vector_type(8)));
typedef float    f32x4 __attribute__((ext_vector_type(4)));

__device__ __forceinline__ float fast_sigmoid(float x) {
    return __builtin_amdgcn_rcpf(1.f + __expf(-x));
}
__device__ __forceinline__ float fast_tanh(float x) {
    return 1.f - 2.f * __builtin_amdgcn_rcpf(__expf(2.f * x) + 1.f);
}
__device__ __forceinline__ int ld_acq(const int* p) {
    return __hip_atomic_load(p, __ATOMIC_ACQUIRE, __HIP_MEMORY_SCOPE_AGENT);
}
__device__ __forceinline__ void st_rel(int* p, int v) {
    __hip_atomic_store(p, v, __ATOMIC_RELEASE, __HIP_MEMORY_SCOPE_AGENT);
}
__device__ __forceinline__ f16x8 zero8() {
    f16x8 v;
    #pragma unroll
    for (int i = 0; i < 8; ++i) v[i] = (_Float16)0.f;
    return v;
}
__device__ __forceinline__ f16x8 cvt8(float4 a, float4 b) {
    f16x8 v;
    v[0] = (_Float16)a.x; v[1] = (_Float16)a.y;
    v[2] = (_Float16)a.z; v[3] = (_Float16)a.w;
    v[4] = (_Float16)b.x; v[5] = (_Float16)b.y;
    v[6] = (_Float16)b.z; v[7] = (_Float16)b.w;
    return v;
}
__device__ __forceinline__ f16x8 cvt4z(float4 a) {
    f16x8 v = zero8();
    v[0] = (_Float16)a.x; v[1] = (_Float16)a.y;
    v[2] = (_Float16)a.z; v[3] = (_Float16)a.w;
    return v;
}

// ---------------------------------------------------------------------------
// stage_kernel: 124 blocks x 512 threads.
//   blocks 0..3   : lstm layer l (serial recurrence, Whh only)
//   blocks 4..123 : proj workers, p = bid-4 -> l = p/30, t = p%30
// Workers compute xp tile [16][400] via MFMA f16 into a 4-slot ring per
// layer; lstm blocks consume via flags.
// ---------------------------------------------------------------------------
__global__ __attribute__((amdgpu_waves_per_eu(1, 2))) __launch_bounds__(512)
void stage_kernel(
    const float* __restrict__ xin,    // [480][640] stage input
    const float* __restrict__ Wih0,   // [400][640]
    const float* __restrict__ WihR,   // [3][400][100]
    const float* __restrict__ Whh,    // [4][400][100]
    const float* __restrict__ bih,    // [4][400]
    const float* __restrict__ bhh,    // [4][400]
    float* __restrict__ ring,         // [4][RING][16][400]
    _Float16* __restrict__ hseq16,    // [4][480][104] (cols 100..103 zero)
    int* __restrict__ flags)          // [128]
{
    const int bid = blockIdx.x;
    const int tid = threadIdx.x;
    int* hflag  = flags;        // [4]
    int* rdflag = flags + 4;    // [4]
    int* xpflag = flags + 8;    // [120]

    if (bid >= 4) {
        // ================= proj worker (MFMA, 8 waves) =================
        const int p  = bid - 4;
        const int l  = p / NTILE;
        const int t  = p % NTILE;
        const int t0 = t * TILE;
        const int lane = tid & 63;
        const int wid  = tid >> 6;      // 0..7
        const int col  = lane & 15;
        const int kb   = lane >> 4;     // 0..3

        if (l > 0) {
            while (ld_acq(&hflag[l - 1]) < t0 + TILE) __builtin_amdgcn_s_sleep(8);
        }
        if (t >= RING) {
            while (ld_acq(&rdflag[l]) < t - (RING - 1)) __builtin_amdgcn_s_sleep(8);
        }

        float* slot = ring + ((size_t)l * RING + (t & (RING - 1))) * (TILE * G4);

        if (l == 0) {
            f16x8 af[20];
            const float* arow = xin + (size_t)(t0 + col) * INP;
            #pragma unroll
            for (int ks = 0; ks < 20; ++ks) {
                const float* ap = arow + ks * 32 + kb * 8;
                af[ks] = cvt8(*(const float4*)ap, *(const float4*)(ap + 4));
            }
            for (int tile = wid; tile < 25; tile += 8) {
                const int n = tile * 16 + col;
                const float* brow = Wih0 + (size_t)n * INP;
                const float bn = bih[n] + bhh[n];
                f32x4 acc = {bn, bn, bn, bn};
                #pragma unroll
                for (int ks = 0; ks < 20; ++ks) {
                    const float* bp = brow + ks * 32 + kb * 8;
                    f16x8 bf = cvt8(*(const float4*)bp, *(const float4*)(bp + 4));
                    acc = __builtin_amdgcn_mfma_f32_16x16x32_f16(af[ks], bf, acc, 0, 0, 0);
                }
                const int u = n % 100, g = n / 100;
                #pragma unroll
                for (int r = 0; r < 4; ++r)
                    slot[(size_t)(kb * 4 + r) * G4 + u * 4 + g] = acc[r];
            }
        } else {
            f16x8 af[4];
            const _Float16* arow = hseq16 + ((size_t)(l - 1) * SEQ + t0 + col) * 104;
            af[0] = *(const f16x8*)(arow + kb * 8);
            af[1] = *(const f16x8*)(arow + 32 + kb * 8);
            af[2] = *(const f16x8*)(arow + 64 + kb * 8);
            af[3] = (kb == 0) ? *(const f16x8*)(arow + 96) : zero8();
            for (int tile = wid; tile < 25; tile += 8) {
                const int n = tile * 16 + col;
                const float* brow = WihR + ((size_t)(l - 1) * G4 + n) * HID;
                const float bn = bih[l * G4 + n] + bhh[l * G4 + n];
                f32x4 acc = {bn, bn, bn, bn};
                #pragma unroll
                for (int ks = 0; ks < 3; ++ks) {
                    const float* bp = brow + ks * 32 + kb * 8;
                    f16x8 bf = cvt8(*(const float4*)bp, *(const float4*)(bp + 4));
                    acc = __builtin_amdgcn_mfma_f32_16x16x32_f16(af[ks], bf, acc, 0, 0, 0);
                }
                f16x8 bf3 = (kb == 0) ? cvt4z(*(const float4*)(brow + 96)) : zero8();
                acc = __builtin_amdgcn_mfma_f32_16x16x32_f16(af[3], bf3, acc, 0, 0, 0);
                const int u = n % 100, g = n / 100;
                #pragma unroll
                for (int r = 0; r < 4; ++r)
                    slot[(size_t)(kb * 4 + r) * G4 + u * 4 + g] = acc[r];
            }
        }
        __syncthreads();   // drain stores (compiler emits vmcnt(0))
        if (tid == 0) st_rel(&xpflag[p], 1);
        return;
    }

    // ============ lstm layer block (512 thr, 8 waves) ============
    // quad = tid>>7: gp = quad>>1 (gates 2gp,2gp+1), kh = quad&1 (k-half).
    // j = tid&127 (unit). Owner = quad 0 (gates i,f; k-half 0), j<100.
    __shared__ __align__(16) float xp_lds[TILE * G4];   // 25.6 KB
    __shared__ __align__(16) uint  hf16[17][64];        // h rows, f16x2 packed
    __shared__ __align__(16) float2 parts[3][104];      // partial gate sums

    const int l    = bid;
    const int quad = tid >> 7;
    const int gp   = quad >> 1;
    const int kh   = quad & 1;
    const int j    = tid & 127;
    const int lane = tid & 63;
    const int kh26 = kh * 26;
    const bool own = (quad == 0) && (j < 100);

    // ---- weights: 2 gates x 52 k as f16x2 (52 VGPRs) ----
    h2t wv[2][26];
    const int jj = (j < 100) ? j : 99;
    #pragma unroll
    for (int g = 0; g < 2; ++g) {
        const float* row =
            Whh + ((size_t)(l * G4 + (gp * 2 + g) * 100 + jj)) * HID + kh * 52;
        #pragma unroll
        for (int q = 0; q < 13; ++q) {
            float4 f = (kh == 0 || q < 12) ? *(const float4*)(row + 4 * q)
                                           : make_float4(0.f, 0.f, 0.f, 0.f);
            wv[g][2 * q]     = h2t{(_Float16)f.x, (_Float16)f.y};
            wv[g][2 * q + 1] = h2t{(_Float16)f.z, (_Float16)f.w};
        }
    }

    for (int i = tid; i < 17 * 64; i += 512) ((uint*)hf16)[i] = 0u;
    float c = 0.f;
    _Float16* hseq_own = hseq16 + (size_t)l * SEQ * 104;
    __syncthreads();

    for (int t = 0; t < NTILE; ++t) {
        const int t0 = t * TILE;

        // ---- wait xp tile, copy ring -> LDS ----
        while (ld_acq(&xpflag[l * NTILE + t]) < 1) __builtin_amdgcn_s_sleep(2);
        {
            const float4* src = (const float4*)(ring +
                ((size_t)l * RING + (t & (RING - 1))) * (TILE * G4));
            float4* dst = (float4*)xp_lds;
            for (int i = tid; i < TILE * G4 / 4; i += 512) dst[i] = src[i];
        }
        __syncthreads();
        if (tid == 0) st_rel(&rdflag[l], t + 1);

        // ---- 16 recurrent steps ----
        for (int tt = 0; tt < TILE; ++tt) {
            // distributed h read: lane c (c<13) holds dwords 2c,2c+1 of half
            uint2 hv = *(const uint2*)(&hf16[tt][kh26 + ((lane & 15) << 1)]);

            float a0e = 0.f, a0o = 0.f, a1e = 0.f, a1o = 0.f;
            #pragma unroll
            for (int cc = 0; cc < 13; ++cc) {
                uint ue = (uint)__builtin_amdgcn_readlane((int)hv.x, cc);
                uint uo = (uint)__builtin_amdgcn_readlane((int)hv.y, cc);
                h2t he = __builtin_bit_cast(h2t, ue);
                h2t ho = __builtin_bit_cast(h2t, uo);
                a0e = __builtin_amdgcn_fdot2(wv[0][2 * cc],     he, a0e, false);
                a0o = __builtin_amdgcn_fdot2(wv[0][2 * cc + 1], ho, a0o, false);
                a1e = __builtin_amdgcn_fdot2(wv[1][2 * cc],     he, a1e, false);
                a1o = __builtin_amdgcn_fdot2(wv[1][2 * cc + 1], ho, a1o, false);
            }
            const float p0 = a0e + a0o;
            const float p1 = a1e + a1o;
            if (quad > 0 && j < 100)
                parts[quad - 1][j] = make_float2(p0, p1);
            __syncthreads();

            if (own) {
                float2 q0 = parts[0][j];   // i,f  k-half1
                float2 q1 = parts[1][j];   // g,o  k-half0
                float2 q2 = parts[2][j];   // g,o  k-half1
                float4 xq = *(const float4*)(xp_lds + tt * G4 + (j << 2));
                float gi = p0 + q0.x + xq.x;
                float gf = p1 + q0.y + xq.y;
                float gg = q1.x + q2.x + xq.z;
                float go = q1.y + q2.y + xq.w;
                float si = fast_sigmoid(gi);
                float sf = fast_sigmoid(gf);
                float so = fast_sigmoid(go);
                float tg = fast_tanh(gg);
                c = sf * c + si * tg;
                float h = so * fast_tanh(c);
                ((_Float16*)&hf16[tt + 1][0])[j] = (_Float16)h;
            }
            __syncthreads();
        }

        // ---- flush rows 1..16 -> hseq16[t0..t0+15]; roll row16 -> row0 ----
        for (int i = tid; i < 16 * 52; i += 512) {
            const int rr = i / 52, dd = i % 52;
            ((uint*)hseq_own)[(size_t)(t0 + rr) * 52 + dd] = hf16[rr + 1][dd];
        }
        if (tid < 52) hf16[0][tid] = hf16[16][tid];
        __syncthreads();   // drains global stores (vmcnt(0)) + LDS
        if (tid == 0) st_rel(&hflag[l], t0 + TILE);
    }
}

// ---------------------------------------------------------------------------
// fc_blend: out[c] = dot(h_last, fcW[c]) + fcb[c]; optional (.+blend)*0.5
// ---------------------------------------------------------------------------
__global__ __launch_bounds__(256) void fc_blend(
    const _Float16* __restrict__ hlast,  // [104] padded row
    const float* __restrict__ fcW,       // [NCLS][HID]
    const float* __restrict__ fcb,       // [NCLS]
    const float* __restrict__ blend,     // [NCLS] or nullptr
    float* __restrict__ outp, int do_blend)
{
    __shared__ __align__(16) float h_lds[HID + 4];
    const int tid = threadIdx.x;
    if (tid < 104) h_lds[tid] = (tid < 100) ? (float)hlast[tid] : 0.f;
    __syncthreads();

    const int cidx = blockIdx.x * 256 + tid;
    const float4* wr = reinterpret_cast<const float4*>(fcW + (size_t)cidx * HID);
    float acc = fcb[cidx];
    #pragma unroll
    for (int k = 0; k < 25; ++k) {
        float4 w4 = wr[k];
        float4 h4 = reinterpret_cast<const float4*>(h_lds)[k];
        acc = fmaf(w4.x, h4.x, acc);
        acc = fmaf(w4.y, h4.y, acc);
        acc = fmaf(w4.z, h4.z, acc);
        acc = fmaf(w4.w, h4.w, acc);
    }
    if (do_blend) acc = (acc + blend[cidx]) * 0.5f;
    outp[cidx] = acc;
}

// ---------------------------------------------------------------------------
extern "C" void kernel_launch(void* const* d_in, const int* in_sizes, int n_in,
                              void* d_out, int out_size, void* d_ws, size_t ws_size,
                              hipStream_t stream)
{
    const float* x    = (const float*)d_in[0];
    const float* xn   = (const float*)d_in[1];
    const float* xnn  = (const float*)d_in[2];
    const float* Wih0 = (const float*)d_in[3];  // (3, 400, 640)
    const float* WihR = (const float*)d_in[4];  // (3, 3, 400, 100)
    const float* Whh  = (const float*)d_in[5];  // (3, 4, 400, 100)
    const float* bih  = (const float*)d_in[6];  // (3, 4, 400)
    const float* bhh  = (const float*)d_in[7];  // (3, 4, 400)
    const float* fcW  = (const float*)d_in[8];  // (3, 307200, 100)
    const float* fcb  = (const float*)d_in[9];  // (3, 307200)
    float* outp = (float*)d_out;
    float* ws = (float*)d_ws;

    float*     ring   = ws;                                  // 102400 f32
    _Float16*  hseq16 = (_Float16*)(ws + 102400);            // 199680 f16
    float*     cur    = ws + 102400 + 99840;                 // 307200 f32
    int*       flags  = (int*)(ws + 102400 + 99840 + 307200);// 3*128 ints

    hipMemsetAsync(flags, 0, 3 * 128 * sizeof(int), stream);

    for (int s = 0; s < 3; ++s) {
        const float* stage_in = (s == 0) ? x : cur;

        stage_kernel<<<4 + 120, 512, 0, stream>>>(
            stage_in,
            Wih0 + (size_t)s * G4 * INP,
            WihR + (size_t)s * 3 * G4 * HID,
            Whh  + (size_t)s * 4 * G4 * HID,
            bih  + (size_t)s * 4 * G4,
            bhh  + (size_t)s * 4 * G4,
            ring, hseq16, flags + s * 128);

        const float* blend = (s == 0) ? xn : (s == 1) ? xnn : nullptr;
        float* dst = (s == 2) ? outp : cur;
        fc_blend<<<NCLS / 256, 256, 0, stream>>>(
            hseq16 + ((size_t)3 * SEQ + SEQ - 1) * 104,
            fcW + (size_t)s * NCLS * HID, fcb + (size_t)s * NCLS,
            blend, dst, (s < 2) ? 1 : 0);
    }
}